// Round 7
// baseline (740.363 us; speedup 1.0000x reference)
//
#include <hip/hip_runtime.h>

// Problem constants (B=16, T=2048 fixed by setup_inputs)
constexpr int NB = 16;
constexpr int NT = 2048;
constexpr int KPROP = 2000;
constexpr int CAND_CAP = 16384;      // observed ~4-5K candidates/batch (3x margin)

// ---------------------------------------------------------------------------
// ws layout (bytes):
//   0    : gMode[16] int   (1 = threshold scatter, 2 = all-candidates (<K case))
//   64   : gV32[16]  u32   (exact 32-bit K-th score bit pattern)
//   128  : gNd2[16]  int   (ties at V32 still to keep)
//   192  : gCnt[16]  int   (candidate count)
//   4096 : cand[16][16384] u32  (flat = s*2048 + e)   1 MB
// ---------------------------------------------------------------------------

// K1: blocks [16, 2064) zero the 268 MB output (8192 float4 each).
//     Blocks [0, 16): one batch each, 512 threads, fully in-LDS pipeline:
//       select (ordered compaction, R6-verified logic, two 256-halves)
//       -> level-0 hist of score bits[30:20] over valid pairs (monotone lo)
//       -> threshold scan -> collect candidates -> 2 exact 10-bit levels.
__global__ __launch_bounds__(512) void k_main(
        const float* __restrict__ start, const float* __restrict__ end,
        float4* __restrict__ out4,
        int* __restrict__ gMode, unsigned* __restrict__ gV32,
        int* __restrict__ gNd2, int* __restrict__ gCnt,
        unsigned* __restrict__ cand) {
    int blk = blockIdx.x, tid = threadIdx.x;
    if (blk >= NB) {                       // ---- fill path ----
        float4 z = make_float4(0.f, 0.f, 0.f, 0.f);
        size_t base = (size_t)(blk - NB) * 8192 + tid;
        #pragma unroll
        for (int it = 0; it < 16; it++) out4[base + (size_t)it * 512] = z;
        return;
    }
    // ---- work path: batch b ----
    int b = blk;
    __shared__ int   lsI[NT]; __shared__ float lsV[NT];   // start anchors (idx-sorted)
    __shared__ int   leI[NT]; __shared__ float leV[NT];   // end anchors (idx-sorted)
    __shared__ unsigned hist[2][2049];                    // level-0, 2 replicas
    __shared__ unsigned h2[1024];                         // levels 1-2
    __shared__ float red2[2][256];
    __shared__ int   sc2[2][256];
    __shared__ int   cs[256];
    __shared__ int   sN[2];
    __shared__ int   sV0, sNd, scnt;
    __shared__ unsigned sTmp;
    __shared__ int   sNd2;

    // ---------- select (R6 k_select logic, one 256-thread half per row) ----------
    int w = tid >> 8, t = tid & 255;
    const float* p = (w ? end : start) + (size_t)b * NT;
    int*   oI = w ? leI : lsI;
    float* oV = w ? leV : lsV;

    int t0 = t * 8;
    float v[8];
    *(float4*)&v[0] = *(const float4*)&p[t0];
    *(float4*)&v[4] = *(const float4*)&p[t0 + 4];

    float m = v[0];
    #pragma unroll
    for (int k = 1; k < 8; k++) m = fmaxf(m, v[k]);
    red2[w][t] = m;
    __syncthreads();
    for (int s = 128; s > 0; s >>= 1) {
        if (t < s) red2[w][t] = fmaxf(red2[w][t], red2[w][t + s]);
        __syncthreads();
    }
    float thr = 0.5f * red2[w][0];

    float prev = (t == 0)   ? -1.0f : p[t0 - 1];   // t==0: rise pad true
    float next = (t == 255) ? -1.0f : p[t0 + 8];   // t==2047: fall pad true

    bool flag[8];
    int c = 0;
    #pragma unroll
    for (int k = 0; k < 8; k++) {
        float pv = (k == 0) ? prev : v[k - 1];
        float nv = (k == 7) ? next : v[k + 1];
        bool f = ((v[k] > pv) && (v[k] > nv)) || (v[k] > thr);
        flag[k] = f;
        c += f;
    }
    sc2[w][t] = c;
    __syncthreads();
    for (int off = 1; off < 256; off <<= 1) {      // Hillis-Steele inclusive scan
        int val = (t >= off) ? sc2[w][t - off] : 0;
        __syncthreads();
        sc2[w][t] += val;
        __syncthreads();
    }
    int pos = sc2[w][t] - c;                       // exclusive offset
    #pragma unroll
    for (int k = 0; k < 8; k++)
        if (flag[k]) { oI[pos] = t0 + k; oV[pos] = v[k]; pos++; }
    if (t == 255) sN[w] = sc2[w][255];

    // zero hist replicas while we're here
    unsigned* hf = &hist[0][0];
    for (int cc = tid; cc < 2 * 2049; cc += 512) hf[cc] = 0u;
    __syncthreads();

    int mS = sN[0], mE = sN[1];

    // ---------- pass 1: level-0 histogram over valid pairs ----------
    {
        int rep = tid & 1;
        int lo = 0;
        for (int i = 0; i < mS; i++) {
            int s = lsI[i];
            while (lo < mE && leI[lo] < s) lo++;   // uniform monotone advance
            float x = lsV[i];
            for (int j = lo + tid; j < mE; j += 512) {
                unsigned bits = __float_as_uint(x * leV[j]);  // in [0,1): bits>>20 < 2048
                atomicAdd(&hist[rep][bits >> 20], 1u);
            }
        }
    }
    __syncthreads();
    for (int cc = tid; cc < 2048; cc += 512) hist[0][cc] += hist[1][cc];
    __syncthreads();

    // ---------- threshold scan (R6 scan_threshold logic) ----------
    if (tid < 256) {
        int base = tid * 8, sum = 0;
        #pragma unroll
        for (int cc = 0; cc < 8; cc++) sum += (int)hist[0][base + cc];
        cs[tid] = sum;
    }
    __syncthreads();
    if (tid == 0) {
        int nd = KPROP, acc = 0, tc = -1;
        for (int tt = 255; tt >= 0; tt--) {
            if (acc + cs[tt] >= nd) { tc = tt; break; }
            acc += cs[tt];
        }
        int found = -1;
        if (tc >= 0) {
            for (int cc = tc * 8 + 7; cc >= tc * 8; cc--) {
                int cnt = (int)hist[0][cc];
                if (acc + cnt >= nd) { found = cc; break; }
                acc += cnt;
            }
        }
        sV0 = found;
        sNd = nd - acc;               // in [1, hist[found]] when found >= 0
        scnt = 0;
    }
    __syncthreads();
    int V0 = sV0;
    int nd = sNd;
    int V0c = (V0 < 0) ? 0 : V0;      // V0<0: fewer than K valid -> collect ALL valid

    // ---------- pass 2: collect candidates (bucket >= V0c) ----------
    unsigned* cb = cand + b * CAND_CAP;
    {
        int lo = 0;
        for (int i = 0; i < mS; i++) {
            int s = lsI[i];
            while (lo < mE && leI[lo] < s) lo++;
            float x = lsV[i];
            for (int j = lo + tid; j < mE; j += 512) {
                unsigned bits = __float_as_uint(x * leV[j]);
                if ((int)(bits >> 20) >= V0c) {
                    int pp = atomicAdd(&scnt, 1);
                    if (pp < CAND_CAP) cb[pp] = (unsigned)(s * NT + leI[j]);
                }
            }
        }
    }
    __syncthreads();
    int n = min(scnt, CAND_CAP);

    if (V0 < 0) {                      // <K valid pairs: K2 writes every candidate
        if (tid == 0) { gMode[b] = 2; gCnt[b] = n; }
        return;
    }

    // ---------- levels 1 & 2 (R6 k_final logic, 512-stride) ----------
    const float* sp = start + (size_t)b * NT;
    const float* ep = end   + (size_t)b * NT;

    // level 1: bits[19:10] among in-bucket candidates
    for (int cc = tid; cc < 1024; cc += 512) h2[cc] = 0u;
    __syncthreads();
    for (int k = tid; k < n; k += 512) {
        unsigned flat = cb[k];
        unsigned bits = __float_as_uint(sp[flat >> 11] * ep[flat & 2047]);
        if ((bits >> 20) == (unsigned)V0) atomicAdd(&h2[(bits >> 10) & 1023], 1u);
    }
    __syncthreads();
    if (tid < 256) {
        int base = tid * 4, s2 = 0;
        #pragma unroll
        for (int cc = 0; cc < 4; cc++) s2 += (int)h2[base + cc];
        cs[tid] = s2;
    }
    __syncthreads();
    if (tid == 0) {
        int acc = 0, tc = 0;
        for (int tt = 255; tt >= 0; tt--) { if (acc + cs[tt] >= nd) { tc = tt; break; } acc += cs[tt]; }
        int found = tc * 4;
        for (int cc = tc * 4 + 3; cc >= tc * 4; cc--) {
            int cnt = (int)h2[cc];
            if (acc + cnt >= nd) { found = cc; break; }
            acc += cnt;
        }
        sTmp = (unsigned)found;  sNd2 = nd - acc;
    }
    __syncthreads();
    unsigned pref10 = ((unsigned)V0 << 10) | sTmp;
    int nd1 = sNd2;

    // level 2: bits[9:0]
    for (int cc = tid; cc < 1024; cc += 512) h2[cc] = 0u;
    __syncthreads();
    for (int k = tid; k < n; k += 512) {
        unsigned flat = cb[k];
        unsigned bits = __float_as_uint(sp[flat >> 11] * ep[flat & 2047]);
        if ((bits >> 10) == pref10) atomicAdd(&h2[bits & 1023], 1u);
    }
    __syncthreads();
    if (tid < 256) {
        int base = tid * 4, s2 = 0;
        #pragma unroll
        for (int cc = 0; cc < 4; cc++) s2 += (int)h2[base + cc];
        cs[tid] = s2;
    }
    __syncthreads();
    if (tid == 0) {
        int acc = 0, tc = 0;
        for (int tt = 255; tt >= 0; tt--) { if (acc + cs[tt] >= nd1) { tc = tt; break; } acc += cs[tt]; }
        int found = tc * 4;
        for (int cc = tc * 4 + 3; cc >= tc * 4; cc--) {
            int cnt = (int)h2[cc];
            if (acc + cnt >= nd1) { found = cc; break; }
            acc += cnt;
        }
        gV32[b] = (pref10 << 10) | (unsigned)found;  // exact K-th score bits
        gNd2[b] = nd1 - acc;                         // ties to keep at V32
        gMode[b] = 1;
        gCnt[b]  = n;
    }
}

// K2: scatter 1.0s (strictly after K1's fill). mode 1: winners > V32 plus the
// nd2 lowest-flat-index ties == V32 (lax.top_k order). mode 2: all candidates.
__global__ __launch_bounds__(512) void k_emit(
        const float* __restrict__ start, const float* __restrict__ end,
        const int* __restrict__ gMode, const unsigned* __restrict__ gV32,
        const int* __restrict__ gNd2, const int* __restrict__ gCnt,
        const unsigned* __restrict__ cand, float* __restrict__ out) {
    int b = blockIdx.x, tid = threadIdx.x;
    int md = gMode[b];
    int n = gCnt[b];
    const unsigned* cb = cand + b * CAND_CAP;

    if (md == 2) {                       // <K valid: every candidate wins
        for (int k = tid; k < n; k += 512) {
            unsigned f = cb[k];
            int s = (int)(f >> 11), e = (int)(f & 2047u);
            out[((size_t)b * NT + (e - s)) * NT + s] = 1.0f;
        }
        return;
    }

    __shared__ unsigned tie[2048];
    __shared__ int tieCnt;
    if (tid == 0) tieCnt = 0;
    __syncthreads();

    unsigned V32 = gV32[b];
    int nd2 = gNd2[b];
    const float* sp = start + (size_t)b * NT;
    const float* ep = end   + (size_t)b * NT;

    for (int k = tid; k < n; k += 512) {
        unsigned f = cb[k];
        int s = (int)(f >> 11), e = (int)(f & 2047u);
        unsigned bits = __float_as_uint(sp[s] * ep[e]);
        if (bits > V32) {
            out[((size_t)b * NT + (e - s)) * NT + s] = 1.0f;
        } else if (bits == V32) {
            int pp = atomicAdd(&tieCnt, 1);
            if (pp < 2048) tie[pp] = f;
        }
    }
    __syncthreads();
    int tn = min(tieCnt, 2048);
    for (int k = tid; k < tn; k += 512) {
        unsigned f = tie[k];
        int rank = 0;
        for (int j = 0; j < tn; j++) rank += (tie[j] < f) ? 1 : 0;
        if (rank < nd2) {                // lowest flat indices win (lax.top_k)
            int s = (int)(f >> 11), e = (int)(f & 2047u);
            out[((size_t)b * NT + (e - s)) * NT + s] = 1.0f;
        }
    }
}

extern "C" void kernel_launch(void* const* d_in, const int* in_sizes, int n_in,
                              void* d_out, int out_size, void* d_ws, size_t ws_size,
                              hipStream_t stream) {
    const float* start = (const float*)d_in[0];
    const float* end   = (const float*)d_in[1];
    // d_in[2] (actionness) unused by the reference.
    float* out = (float*)d_out;
    char* ws = (char*)d_ws;

    int*      gMode = (int*)     (ws + 0);
    unsigned* gV32  = (unsigned*)(ws + 64);
    int*      gNd2  = (int*)     (ws + 128);
    int*      gCnt  = (int*)     (ws + 192);
    unsigned* cand  = (unsigned*)(ws + 4096);

    // K1: 16 per-batch work blocks + 2048 fill blocks (268 MB zero);
    //     per-batch work hides under the fill.
    k_main<<<NB + 2048, 512, 0, stream>>>(start, end, (float4*)out,
                                          gMode, gV32, gNd2, gCnt, cand);
    // K2: scatter winners/ties, strictly after the fill completes.
    k_emit<<<NB, 512, 0, stream>>>(start, end, gMode, gV32, gNd2, gCnt, cand, out);
}

// Round 8
// 153.993 us; speedup vs baseline: 4.8078x; 4.8078x over previous
//
#include <hip/hip_runtime.h>

// Problem constants (B=16, T=2048 fixed by setup_inputs)
constexpr int NB = 16;
constexpr int NT = 2048;
constexpr int KPROP = 2000;
constexpr int CAND_CAP = 8192;          // observed ~4-5K candidates/batch
constexpr int HIST_U32 = NB * 2048;     // 32768 words
constexpr int CC_STRIDE = 32;           // candCnt padded: 1 counter per 128 B

// ---------------------------------------------------------------------------
// Workspace layout (bytes), ~1.13 MB:
//   0       : nS[16]          (int)
//   64      : nE[16]          (int)
//   128     : candCnt[16*32]  (int, padded; index b*32)
//   4096    : hist[16][2048]  u32
//   135168  : sIdx[16][2048]  int
//   266240  : sVal[16][2048]  f32
//   397312  : eIdx[16][2048]  int   (position-sorted ascending)
//   528384  : eVal[16][2048]  f32
//   659456  : cand[16][8192]  u32   (flat = s*2048+e)
// ---------------------------------------------------------------------------

// Anchor selection with ORDERED compaction (prefix scan, deterministic,
// position-sorted output) + zeroing of hist & counters.  [verified R4/R6]
__global__ void k_select(const float* __restrict__ start, const float* __restrict__ end,
                         int* nS, int* nE, int* candCnt,
                         unsigned* hist, int* sIdx, float* sVal, int* eIdx, float* eVal) {
    int b = blockIdx.x, which = blockIdx.y;
    const float* p = (which ? end : start) + (size_t)b * NT;
    int* nArr = which ? nE : nS;
    int* idxArr = (which ? eIdx : sIdx) + b * NT;
    float* valArr = (which ? eVal : sVal) + b * NT;
    int tid = threadIdx.x;

    // cooperative zero of hist region + padded counters
    int gid = (which * NB + b) * 256 + tid;               // 0..8191
    for (int h = gid; h < HIST_U32; h += NB * 2 * 256) hist[h] = 0u;
    if (gid < NB * CC_STRIDE) candCnt[gid] = 0;

    int t0 = tid * 8;
    float v[8];
    *(float4*)&v[0] = *(const float4*)&p[t0];
    *(float4*)&v[4] = *(const float4*)&p[t0 + 4];

    // row max
    __shared__ float red[256];
    float m = v[0];
    #pragma unroll
    for (int k = 1; k < 8; k++) m = fmaxf(m, v[k]);
    red[tid] = m;
    __syncthreads();
    for (int s = 128; s > 0; s >>= 1) {
        if (tid < s) red[tid] = fmaxf(red[tid], red[tid + s]);
        __syncthreads();
    }
    float thr = 0.5f * red[0];

    float prev = (tid == 0)   ? -1.0f : p[t0 - 1];   // t==0: rise pad true
    float next = (tid == 255) ? -1.0f : p[t0 + 8];   // t==2047: fall pad true

    bool flag[8];
    int c = 0;
    #pragma unroll
    for (int k = 0; k < 8; k++) {
        float pv = (k == 0) ? prev : v[k - 1];
        float nv = (k == 7) ? next : v[k + 1];
        bool f = ((v[k] > pv) && (v[k] > nv)) || (v[k] > thr);
        flag[k] = f;
        c += f;
    }

    // block-wide inclusive scan of per-thread counts (Hillis-Steele)
    __shared__ int sc[256];
    sc[tid] = c;
    __syncthreads();
    for (int off = 1; off < 256; off <<= 1) {
        int val = (tid >= off) ? sc[tid - off] : 0;
        __syncthreads();
        sc[tid] += val;
        __syncthreads();
    }
    int pos = sc[tid] - c;   // exclusive offset
    #pragma unroll
    for (int k = 0; k < 8; k++) {
        if (flag[k]) { idxArr[pos] = t0 + k; valArr[pos] = v[k]; pos++; }
    }
    if (tid == 255) nArr[b] = sc[255];
}

// Level-0 histogram of score bits[30:20] over all VALID pairs, fused with
// zeroing ALL of out (268 MB). e-list staged in LDS: binary searches are
// ~11 LDS reads (not 11 dependent global loads). 4 replica hists cut
// same-address atomic serialization.
__global__ void k_hist0(const int* __restrict__ nS, const int* __restrict__ nE,
                        const int* __restrict__ sIdx, const float* __restrict__ sVal,
                        const int* __restrict__ eIdx, const float* __restrict__ eVal,
                        unsigned* __restrict__ hist, float4* __restrict__ out4) {
    int b = blockIdx.y, tid = threadIdx.x;
    int blockId = b * gridDim.x + blockIdx.x;             // 0..1023
    {   // zero 16,777,216 float4 (268 MB): 16384 per block, 64 per thread
        float4 z = make_float4(0.f, 0.f, 0.f, 0.f);
        size_t base = (size_t)blockId * 16384 + tid;
        #pragma unroll
        for (int it = 0; it < 64; it++) out4[base + it * 256] = z;
    }
    __shared__ unsigned shist[4][2049];                   // replicas, bank-spread
    __shared__ float sEv[NT];
    __shared__ int   sEi[NT];
    unsigned* shf = &shist[0][0];
    for (int c = tid; c < 4 * 2049; c += 256) shf[c] = 0u;

    int ns = nS[b], ne = nE[b];
    const int* si = sIdx + b * NT;
    const float* sv = sVal + b * NT;
    const int* ei = eIdx + b * NT;
    const float* ev = eVal + b * NT;
    for (int c = tid; c < ne; c += 256) { sEv[c] = ev[c]; sEi[c] = ei[c]; }
    __syncthreads();

    int rep = tid & 3;
    for (int i = blockIdx.x; i < ns; i += gridDim.x) {
        int s = si[i];
        float x = sv[i];
        int lo = 0, hi = ne;                               // first j with eIdx[j] >= s
        while (lo < hi) { int mid = (lo + hi) >> 1; if (sEi[mid] < s) lo = mid + 1; else hi = mid; }
        for (int j = lo + tid; j < ne; j += 256) {
            unsigned bits = __float_as_uint(x * sEv[j]);   // in [0,1): bits>>20 < 2048
            atomicAdd(&shist[rep][bits >> 20], 1u);
        }
    }
    __syncthreads();
    unsigned* h = hist + b * 2048;
    for (int c = tid; c < 2048; c += 256) {
        unsigned x = shist[0][c] + shist[1][c] + shist[2][c] + shist[3][c];
        if (x) atomicAdd(&h[c], x);
    }
}

// Descending scan of one batch's 2048-bucket histogram (deterministic; every
// block re-derives the same (V0, nd)). Returns V0 (-1 iff total < K).  [verified R6]
__device__ int scan_threshold(const unsigned* __restrict__ h, int tid,
                              int* cs, int* sV0, int* sNd) {
    int base = tid * 8, sum = 0;
    #pragma unroll
    for (int c = 0; c < 8; c++) sum += (int)h[base + c];
    cs[tid] = sum;
    __syncthreads();
    if (tid == 0) {
        int nd = KPROP, acc = 0, tc = -1;
        for (int t = 255; t >= 0; t--) {
            if (acc + cs[t] >= nd) { tc = t; break; }
            acc += cs[t];
        }
        int found = -1;
        if (tc >= 0) {
            for (int c = tc * 8 + 7; c >= tc * 8; c--) {
                int cnt = (int)h[c];
                if (acc + cnt >= nd) { found = c; break; }
                acc += cnt;
            }
        }
        *sV0 = found;
        *sNd = nd - acc;               // in [1, h[found]] when found >= 0
    }
    __syncthreads();
    return *sV0;
}

// Collect candidates (bucket >= V0). e-list in LDS; LDS-buffered output with
// one global atomic per block (plus rare guarded spills).  [verified R4/R6 + LDS e-list]
__global__ void k_collect(const int* __restrict__ nS, const int* __restrict__ nE,
                          const int* __restrict__ sIdx, const float* __restrict__ sVal,
                          const int* __restrict__ eIdx, const float* __restrict__ eVal,
                          const unsigned* __restrict__ hist,
                          int* candCnt, unsigned* cand) {
    constexpr int LCAP = 4096;
    __shared__ unsigned lbuf[LCAP];
    __shared__ float sEv[NT];
    __shared__ int   sEi[NT];
    __shared__ int cs[256];
    __shared__ int sV0, sNd;
    __shared__ int lcnt;
    __shared__ int sBase;
    int b = blockIdx.y, tid = threadIdx.x;

    int ns = nS[b], ne = nE[b];
    const int* si = sIdx + b * NT;
    const float* sv = sVal + b * NT;
    const int* ei = eIdx + b * NT;
    const float* ev = eVal + b * NT;
    for (int c = tid; c < ne; c += 256) { sEv[c] = ev[c]; sEi[c] = ei[c]; }

    int V0 = scan_threshold(hist + b * 2048, tid, cs, &sV0, &sNd);
    if (V0 < 0) return;               // <K valid pairs: k_final writes all valid
    if (tid == 0) lcnt = 0;
    __syncthreads();

    int* cc = candCnt + b * CC_STRIDE;

    for (int i = blockIdx.x; i < ns; i += gridDim.x) {
        int s = si[i];
        float x = sv[i];
        int lo = 0, hi = ne;
        while (lo < hi) { int mid = (lo + hi) >> 1; if (sEi[mid] < s) lo = mid + 1; else hi = mid; }
        for (int j = lo + tid; j < ne; j += 256) {
            unsigned bits = __float_as_uint(x * sEv[j]);
            if ((bits >> 20) >= (unsigned)V0) {
                int pos = atomicAdd(&lcnt, 1);
                if (pos < LCAP) {
                    lbuf[pos] = (unsigned)(s * NT + sEi[j]);
                } else {                                   // rare spill path
                    int g = atomicAdd(cc, 1);
                    if (g < CAND_CAP) cand[b * CAND_CAP + g] = (unsigned)(s * NT + sEi[j]);
                }
            }
        }
    }
    __syncthreads();
    int cnt = min(lcnt, LCAP);
    if (tid == 0) sBase = atomicAdd(cc, cnt);
    __syncthreads();
    int base = sBase;
    for (int k = tid; k < cnt; k += 256) {
        int g = base + k;
        if (g < CAND_CAP) cand[b * CAND_CAP + g] = lbuf[k];
    }
}

// Exact selection among candidates: two 10-bit radix levels (scores recomputed
// from start/end), write 1.0 winners, flat-rank tie-break.  [verified R6]
__global__ void k_final(const float* __restrict__ start, const float* __restrict__ end,
                        const int* __restrict__ nS, const int* __restrict__ nE,
                        const int* __restrict__ sIdx, const int* __restrict__ eIdx,
                        const unsigned* __restrict__ hist, const int* __restrict__ candCnt,
                        const unsigned* __restrict__ cand, float* __restrict__ out) {
    int b = blockIdx.x, tid = threadIdx.x;
    const float* sp = start + (size_t)b * NT;
    const float* ep = end   + (size_t)b * NT;

    __shared__ unsigned h[1024];
    __shared__ int cs[256];
    __shared__ unsigned tie[1024];
    __shared__ int tieCnt;
    __shared__ unsigned sTmp;
    __shared__ int sNd0, sNd;
    __shared__ int sV0s;

    int V0 = scan_threshold(hist + b * 2048, tid, cs, &sV0s, &sNd0);
    int nd = sNd0;

    if (V0 < 0) {      // <K valid pairs: all valid pairs become 1.0
        int ns = nS[b], ne = nE[b];
        const int* si = sIdx + b * NT;
        const int* ei = eIdx + b * NT;
        for (int i = 0; i < ns; i++) {
            int s = si[i];
            int lo = 0, hi = ne;
            while (lo < hi) { int mid = (lo + hi) >> 1; if (ei[mid] < s) lo = mid + 1; else hi = mid; }
            for (int j = lo + tid; j < ne; j += 256) {
                int e = ei[j];
                out[((size_t)b * NT + (e - s)) * NT + s] = 1.0f;
            }
        }
        return;
    }

    int n = min(candCnt[b * CC_STRIDE], CAND_CAP);

    // ---- level 1: bits[19:10] among in-bucket candidates ----
    for (int c = tid; c < 1024; c += 256) h[c] = 0u;
    __syncthreads();
    for (int k = tid; k < n; k += 256) {
        unsigned flat = cand[b * CAND_CAP + k];
        unsigned bits = __float_as_uint(sp[flat >> 11] * ep[flat & 2047]);
        if ((bits >> 20) == (unsigned)V0) atomicAdd(&h[(bits >> 10) & 1023], 1u);
    }
    __syncthreads();
    { int base = tid * 4, s2 = 0;
      #pragma unroll
      for (int c = 0; c < 4; c++) s2 += (int)h[base + c];
      cs[tid] = s2; }
    __syncthreads();
    if (tid == 0) {
        int acc = 0, tc = 0;
        for (int t = 255; t >= 0; t--) { if (acc + cs[t] >= nd) { tc = t; break; } acc += cs[t]; }
        int found = tc * 4;
        for (int c = tc * 4 + 3; c >= tc * 4; c--) {
            int cnt = (int)h[c];
            if (acc + cnt >= nd) { found = c; break; }
            acc += cnt;
        }
        sTmp = (unsigned)found;  sNd = nd - acc;
    }
    __syncthreads();
    unsigned pref10 = ((unsigned)V0 << 10) | sTmp;
    int nd1 = sNd;

    // ---- level 2: bits[9:0] ----
    for (int c = tid; c < 1024; c += 256) h[c] = 0u;
    __syncthreads();
    for (int k = tid; k < n; k += 256) {
        unsigned flat = cand[b * CAND_CAP + k];
        unsigned bits = __float_as_uint(sp[flat >> 11] * ep[flat & 2047]);
        if ((bits >> 10) == pref10) atomicAdd(&h[bits & 1023], 1u);
    }
    __syncthreads();
    { int base = tid * 4, s2 = 0;
      #pragma unroll
      for (int c = 0; c < 4; c++) s2 += (int)h[base + c];
      cs[tid] = s2; }
    __syncthreads();
    if (tid == 0) {
        int acc = 0, tc = 0;
        for (int t = 255; t >= 0; t--) { if (acc + cs[t] >= nd1) { tc = t; break; } acc += cs[t]; }
        int found = tc * 4;
        for (int c = tc * 4 + 3; c >= tc * 4; c--) {
            int cnt = (int)h[c];
            if (acc + cnt >= nd1) { found = c; break; }
            acc += cnt;
        }
        sTmp = (pref10 << 10) | (unsigned)found;   // exact 32-bit K-th score bits
        sNd  = nd1 - acc;                          // ties still needed at V32
        tieCnt = 0;
    }
    __syncthreads();
    unsigned V32 = sTmp;
    int nd2 = sNd;

    // ---- write winners (> V32), collect exact ties (== V32) ----
    for (int k = tid; k < n; k += 256) {
        unsigned flat = cand[b * CAND_CAP + k];
        int s = flat >> 11, e = flat & 2047;
        unsigned bits = __float_as_uint(sp[s] * ep[e]);
        if (bits > V32) {
            out[((size_t)b * NT + (e - s)) * NT + s] = 1.0f;
        } else if (bits == V32) {
            int pos = atomicAdd(&tieCnt, 1);
            if (pos < 1024) tie[pos] = flat;
        }
    }
    __syncthreads();
    int tn = min(tieCnt, 1024);
    for (int k = tid; k < tn; k += 256) {
        unsigned f = tie[k];
        int rank = 0;
        for (int j = 0; j < tn; j++) rank += (tie[j] < f) ? 1 : 0;
        if (rank < nd2) {                          // lowest flat idx wins (lax.top_k)
            int s = f >> 11, e = f & 2047;
            out[((size_t)b * NT + (e - s)) * NT + s] = 1.0f;
        }
    }
}

extern "C" void kernel_launch(void* const* d_in, const int* in_sizes, int n_in,
                              void* d_out, int out_size, void* d_ws, size_t ws_size,
                              hipStream_t stream) {
    const float* start = (const float*)d_in[0];
    const float* end   = (const float*)d_in[1];
    // d_in[2] (actionness) unused by the reference.
    float* out = (float*)d_out;
    char* ws = (char*)d_ws;

    int*      nS      = (int*)     (ws + 0);
    int*      nE      = (int*)     (ws + 64);
    int*      candCnt = (int*)     (ws + 128);     // padded [16*32]
    unsigned* hist    = (unsigned*)(ws + 4096);
    int*      sIdx    = (int*)     (ws + 135168);
    float*    sVal    = (float*)   (ws + 266240);
    int*      eIdx    = (int*)     (ws + 397312);
    float*    eVal    = (float*)   (ws + 528384);
    unsigned* cand    = (unsigned*)(ws + 659456);

    // 1) anchor selection (ordered compaction) + zero hist/counters
    k_select<<<dim3(NB, 2), 256, 0, stream>>>(start, end, nS, nE, candCnt,
                                              hist, sIdx, sVal, eIdx, eVal);
    // 2) level-0 histogram over valid pairs (LDS e-list, 4-replica hist),
    //    fused with zeroing ALL of out
    k_hist0<<<dim3(64, NB), 256, 0, stream>>>(nS, nE, sIdx, sVal, eIdx, eVal, hist,
                                              (float4*)out);
    // 3) collect candidates (bucket >= V0; V0 re-derived per block; LDS e-list)
    k_collect<<<dim3(64, NB), 256, 0, stream>>>(nS, nE, sIdx, sVal, eIdx, eVal, hist,
                                                candCnt, cand);
    // 4) exact selection + scatter of 1.0s (V0/need re-derived per block)
    k_final<<<NB, 256, 0, stream>>>(start, end, nS, nE, sIdx, eIdx, hist,
                                    candCnt, cand, out);
}